// Round 6
// baseline (3208.455 us; speedup 1.0000x reference)
//
#include <hip/hip_runtime.h>

#define NROWS 16384
#define DIN   1024
#define DH    4096
#define DZ    256
#define KCB   4096

typedef _Float16 f16x8 __attribute__((ext_vector_type(8)));
typedef _Float16 f16x4 __attribute__((ext_vector_type(4)));
typedef float    f32x4 __attribute__((ext_vector_type(4)));

#define INV4096 2.44140625e-4f
#define F16_MIN_NORMAL 6.103515625e-05f

struct Split { _Float16 h, l; };

// Scaled split: v -> (64*hi, 64*resid), both normal-or-zero f16.
// value = (h + l)/64 with h carrying 11 high bits. Products of two stored
// operands land at 4096x true scale -> single fp32 accumulator, /4096 at end.
__device__ inline Split splitf64(float v) {
    float v64 = v * 64.0f;
    _Float16 hh = (_Float16)v64;
    float hf = (float)hh;
    if (fabsf(hf) < F16_MIN_NORMAL) { hh = (_Float16)0.0f; hf = 0.0f; }
    Split s;
    s.h = hh;
    s.l = (_Float16)(v64 - hf);   // exact resid*64, then f16-rounded
    return s;
}

__device__ inline void gload_lds16(const void* g, void* l) {
    __builtin_amdgcn_global_load_lds(
        (const __attribute__((address_space(1))) void*)g,
        (__attribute__((address_space(3))) void*)l, 16, 0, 0);
}

// ---------------------------------------------------------------------------
// init: best = +inf packed, z2 = 0
__global__ void k_init(unsigned long long* best, float* z2) {
    int i = blockIdx.x * 256 + threadIdx.x;
    if (i < NROWS) { best[i] = 0xFFFFFFFFFFFFFFFFULL; z2[i] = 0.0f; }
}

// Element-wise fp32 -> scaled split f16 pair. n multiple of 1024.
__global__ void k_esplit(const float* __restrict__ X, _Float16* __restrict__ H,
                         _Float16* __restrict__ L, size_t n) {
    size_t i = ((size_t)blockIdx.x * 256 + threadIdx.x) * 4;
    if (i >= n) return;
    float4 v = *(const float4*)(X + i);
    f16x4 hv, lv;
    Split s0 = splitf64(v.x), s1 = splitf64(v.y), s2 = splitf64(v.z), s3 = splitf64(v.w);
    hv[0] = s0.h; hv[1] = s1.h; hv[2] = s2.h; hv[3] = s3.h;
    lv[0] = s0.l; lv[1] = s1.l; lv[2] = s2.l; lv[3] = s3.l;
    *(f16x4*)(H + i) = hv;
    *(f16x4*)(L + i) = lv;
}

// Transpose + split: B[K][N] fp32 -> Th/Tl [N][K] f16. K,N multiples of 32.
__global__ void k_tsplit(const float* __restrict__ B, _Float16* __restrict__ Th,
                         _Float16* __restrict__ Tl, int K, int N) {
    __shared__ float tile[32][33];
    const int k0 = blockIdx.x * 32, n0 = blockIdx.y * 32;
    const int tx = threadIdx.x, ty = threadIdx.y;   // block (32,8)
#pragma unroll
    for (int i = 0; i < 4; i++)
        tile[ty + i * 8][tx] = B[(size_t)(k0 + ty + i * 8) * N + n0 + tx];
    __syncthreads();
#pragma unroll
    for (int i = 0; i < 4; i++) {
        float v = tile[tx][ty + i * 8];
        Split s = splitf64(v);
        size_t o = (size_t)(n0 + ty + i * 8) * K + k0 + tx;
        Th[o] = s.h; Tl[o] = s.l;
    }
}

// ---------------------------------------------------------------------------
// Split-precision f16 MFMA GEMM, single accumulator (acc = 4096*C).
// A as Ah/Al [M][K], B as Bh/Bl [N][K] (scaled-split storage).
// Tile BM x 128 (BM = MFRAGS*32), BK=32, 4 waves (2x2), 16x16x32 MFMA.
// MODE 0: Ch/Cl = split(relu(C+bias))
// MODE 1: Ch/Cl = split(C+bias)
// MODE 2: Ch/Cl = split(C+bias) AND z2[row] += sum_col C^2 (atomic)
// MODE 3: d = Z2[m] + C2[n] - 2*C; packed atomicMin(best)
template <int MODE, int MFRAGS>
__global__ __launch_bounds__(256, 3)
void k_gemm_split(const _Float16* __restrict__ Ah, const _Float16* __restrict__ Al,
                  const _Float16* __restrict__ Bh, const _Float16* __restrict__ Bl,
                  const float* __restrict__ bias,
                  _Float16* __restrict__ Ch, _Float16* __restrict__ Cl,
                  float* __restrict__ Z2w,
                  const float* __restrict__ Z2, const float* __restrict__ C2,
                  unsigned long long* __restrict__ best,
                  int M, int N, int K) {
    constexpr int BM = MFRAGS * 32;               // 128 or 64
    __shared__ __align__(16) _Float16 sAh[BM * 32];
    __shared__ __align__(16) _Float16 sAl[BM * 32];
    __shared__ __align__(16) _Float16 sBh[128 * 32];
    __shared__ __align__(16) _Float16 sBl[128 * 32];

    const int tid  = threadIdx.x;
    const int w    = tid >> 6;
    const int l    = tid & 63;
    const int wm   = w >> 1, wn = w & 1;
    const int quad = l >> 4, lcol = l & 15;
    const long m0 = (long)blockIdx.y * BM;
    const long n0 = (long)blockIdx.x * 128;

    // staging assignment: wave w stages one tile
    const _Float16* gsrc; _Float16* ldst; long rbase; int nld;
    if      (w == 0) { gsrc = Ah; ldst = sAh; rbase = m0; nld = BM / 16; }
    else if (w == 1) { gsrc = Al; ldst = sAl; rbase = m0; nld = BM / 16; }
    else if (w == 2) { gsrc = Bh; ldst = sBh; rbase = n0; nld = 8; }
    else             { gsrc = Bl; ldst = sBl; rbase = n0; nld = 8; }
    const _Float16* gbase = gsrc + (rbase + (l >> 2)) * (size_t)K + (l & 3) * 8;

    f32x4 acc[MFRAGS][4];
#pragma unroll
    for (int i = 0; i < MFRAGS; i++)
#pragma unroll
        for (int j = 0; j < 4; j++)
            acc[i][j] = (f32x4){0.f, 0.f, 0.f, 0.f};

    for (int k0 = 0; k0 < K; k0 += 32) {
        for (int u = 0; u < nld; u++)
            gload_lds16(gbase + k0 + (size_t)u * 16 * K, ldst + u * 16 * 32);
        __syncthreads();

        f16x8 fa_h[MFRAGS], fa_l[MFRAGS], fb_h[4], fb_l[4];
#pragma unroll
        for (int fi = 0; fi < MFRAGS; fi++) {
            const int o = (wm * (MFRAGS * 16) + fi * 16 + lcol) * 32 + quad * 8;
            fa_h[fi] = *(const f16x8*)(sAh + o);
            fa_l[fi] = *(const f16x8*)(sAl + o);
        }
#pragma unroll
        for (int fj = 0; fj < 4; fj++) {
            const int o = (wn * 64 + fj * 16 + lcol) * 32 + quad * 8;
            fb_h[fj] = *(const f16x8*)(sBh + o);
            fb_l[fj] = *(const f16x8*)(sBl + o);
        }
#pragma unroll
        for (int fi = 0; fi < MFRAGS; fi++)
#pragma unroll
            for (int fj = 0; fj < 4; fj++) {
                acc[fi][fj] = __builtin_amdgcn_mfma_f32_16x16x32_f16(
                    fa_h[fi], fb_h[fj], acc[fi][fj], 0, 0, 0);
                acc[fi][fj] = __builtin_amdgcn_mfma_f32_16x16x32_f16(
                    fa_h[fi], fb_l[fj], acc[fi][fj], 0, 0, 0);
                acc[fi][fj] = __builtin_amdgcn_mfma_f32_16x16x32_f16(
                    fa_l[fi], fb_h[fj], acc[fi][fj], 0, 0, 0);
            }
        __syncthreads();
    }

    if (MODE != 3) {
#pragma unroll
        for (int fi = 0; fi < MFRAGS; fi++) {
#pragma unroll
            for (int r = 0; r < 4; r++) {
                const long row = m0 + wm * (MFRAGS * 16) + fi * 16 + quad * 4 + r;
                float ss = 0.0f;
#pragma unroll
                for (int fj = 0; fj < 4; fj++) {
                    const long col = n0 + wn * 64 + fj * 16 + lcol;
                    float v = acc[fi][fj][r] * INV4096 + bias[col];
                    if (MODE == 0) v = fmaxf(v, 0.0f);
                    Split s = splitf64(v);
                    const size_t o = (size_t)row * N + col;
                    Ch[o] = s.h; Cl[o] = s.l;
                    if (MODE == 2) ss += v * v;
                }
                if (MODE == 2) {
#pragma unroll
                    for (int off = 1; off < 16; off <<= 1)
                        ss += __shfl_xor(ss, off, 64);
                    if (lcol == 0) atomicAdd(Z2w + row, ss);
                }
            }
        }
    } else {
        float cc2[4];
#pragma unroll
        for (int fj = 0; fj < 4; fj++)
            cc2[fj] = C2[n0 + wn * 64 + fj * 16 + lcol];
#pragma unroll
        for (int fi = 0; fi < MFRAGS; fi++) {
#pragma unroll
            for (int r = 0; r < 4; r++) {
                const long row = m0 + wm * (MFRAGS * 16) + fi * 16 + quad * 4 + r;
                const float zz = Z2[row];
                float dmin = 3.4e38f; int didx = 0x7FFFFFFF;
#pragma unroll
                for (int fj = 0; fj < 4; fj++) {
                    float accv = acc[fi][fj][r] * INV4096;
                    int col = (int)(n0 + wn * 64 + fj * 16 + lcol);
                    float d = (zz + cc2[fj]) - 2.0f * accv;
                    if (d < dmin || (d == dmin && col < didx)) { dmin = d; didx = col; }
                }
#pragma unroll
                for (int off = 1; off < 16; off <<= 1) {
                    float ov = __shfl_xor(dmin, off, 64);
                    int   oi = __shfl_xor(didx, off, 64);
                    if (ov < dmin || (ov == dmin && oi < didx)) { dmin = ov; didx = oi; }
                }
                if (lcol == 0) {
                    unsigned long long pk =
                        ((unsigned long long)__float_as_uint(dmin) << 32) |
                        (unsigned long long)(unsigned)didx;
                    atomicMin(best + row, pk);
                }
            }
        }
    }
}

// ---------------------------------------------------------------------------
__global__ void k_row_sq_norms(const float* __restrict__ X, float* __restrict__ out,
                               int ncols, int nrows) {
    const int wave = threadIdx.x >> 6;
    const int lane = threadIdx.x & 63;
    const long row = (long)blockIdx.x * 4 + wave;
    if (row >= nrows) return;
    const float* p = X + row * (long)ncols;
    float s = 0.0f;
    for (int c = lane * 4; c < ncols; c += 256) {
        float4 v = *(const float4*)(p + c);
        s += v.x * v.x + v.y * v.y + v.z * v.z + v.w * v.w;
    }
#pragma unroll
    for (int off = 32; off > 0; off >>= 1) s += __shfl_down(s, off, 64);
    if (lane == 0) out[row] = s;
}

__global__ void k_loss(const unsigned long long* __restrict__ best,
                       float* __restrict__ out) {
    __shared__ float red[256];
    float s = 0.0f;
    for (int i = threadIdx.x; i < NROWS; i += 256)
        s += __uint_as_float((unsigned)(best[i] >> 32));
    red[threadIdx.x] = s;
    __syncthreads();
    for (int st = 128; st > 0; st >>= 1) {
        if (threadIdx.x < st) red[threadIdx.x] += red[threadIdx.x + st];
        __syncthreads();
    }
    if (threadIdx.x == 0) out[(size_t)NROWS * DZ] = 2.0f * red[0];
}

__global__ void k_output(const float* __restrict__ CB,
                         const unsigned long long* __restrict__ best,
                         float* __restrict__ out) {
    const long n = blockIdx.x;
    const int t = threadIdx.x;      // 64 threads
    const int wd = (int)(unsigned)(best[n] & 0xFFFFFFFFULL);
    float4 v = *(const float4*)(CB + (size_t)wd * DZ + t * 4);
    *(float4*)(out + n * (size_t)DZ + t * 4) = v;
}

// ---------------------------------------------------------------------------
extern "C" void kernel_launch(void* const* d_in, const int* in_sizes, int n_in,
                              void* d_out, int out_size, void* d_ws, size_t ws_size,
                              hipStream_t stream) {
    const float* x  = (const float*)d_in[0];
    const float* W1 = (const float*)d_in[1];
    const float* b1 = (const float*)d_in[2];
    const float* W2 = (const float*)d_in[3];
    const float* b2 = (const float*)d_in[4];
    const float* W3 = (const float*)d_in[5];
    const float* b3 = (const float*)d_in[6];
    const float* cb = (const float*)d_in[7];
    float* out = (float*)d_out;

    // ---- workspace carve-up (bytes, 256-aligned) ----
    char* base = (char*)d_ws;
    size_t off = 0;
    auto alloc = [&](size_t bytes) -> void* {
        void* p = base + off;
        off = (off + bytes + 255) & ~(size_t)255;
        return p;
    };
    // fixed region: weights, codebook, z-split, norms, best (~104 MB)
    _Float16* W1tH = (_Float16*)alloc((size_t)DH * DIN * 2);
    _Float16* W1tL = (_Float16*)alloc((size_t)DH * DIN * 2);
    _Float16* W2tH = (_Float16*)alloc((size_t)DH * DH * 2);
    _Float16* W2tL = (_Float16*)alloc((size_t)DH * DH * 2);
    _Float16* W3tH = (_Float16*)alloc((size_t)DZ * DH * 2);
    _Float16* W3tL = (_Float16*)alloc((size_t)DZ * DH * 2);
    _Float16* cbH  = (_Float16*)alloc((size_t)KCB * DZ * 2);
    _Float16* cbL  = (_Float16*)alloc((size_t)KCB * DZ * 2);
    _Float16* zH   = (_Float16*)alloc((size_t)NROWS * DZ * 2);
    _Float16* zL   = (_Float16*)alloc((size_t)NROWS * DZ * 2);
    float*    z2   = (float*)alloc((size_t)NROWS * 4);
    float*    c2   = (float*)alloc((size_t)KCB * 4);
    unsigned long long* best = (unsigned long long*)alloc((size_t)NROWS * 8);

    // chunk buffers: x split (4 KB/row) + h1/h2 splits (32 KB/row)
    size_t rem = (ws_size > off) ? (ws_size - off) : 0;
    size_t rc = rem / ((size_t)DIN * 2 * 2 + (size_t)DH * 2 * 4);
    rc = (rc / 128) * 128;
    if (rc > NROWS) rc = NROWS;
    if (rc < 128)   rc = 128;
    _Float16* xcH = (_Float16*)alloc((size_t)rc * DIN * 2);
    _Float16* xcL = (_Float16*)alloc((size_t)rc * DIN * 2);
    _Float16* h1H = (_Float16*)alloc((size_t)rc * DH * 2);
    _Float16* h1L = (_Float16*)alloc((size_t)rc * DH * 2);
    _Float16* h2H = (_Float16*)alloc((size_t)rc * DH * 2);
    _Float16* h2L = (_Float16*)alloc((size_t)rc * DH * 2);

    // ---- one-time conversions ----
    k_init<<<(NROWS + 255) / 256, 256, 0, stream>>>(best, z2);
    k_esplit<<<(unsigned)((size_t)KCB * DZ / 1024), 256, 0, stream>>>(
        cb, cbH, cbL, (size_t)KCB * DZ);
    k_tsplit<<<dim3(DIN / 32, DH / 32), dim3(32, 8), 0, stream>>>(W1, W1tH, W1tL, DIN, DH);
    k_tsplit<<<dim3(DH / 32, DH / 32),  dim3(32, 8), 0, stream>>>(W2, W2tH, W2tL, DH, DH);
    k_tsplit<<<dim3(DH / 32, DZ / 32),  dim3(32, 8), 0, stream>>>(W3, W3tH, W3tL, DH, DZ);

    // ---- MLP (chunked over rows) ----
    for (size_t r0 = 0; r0 < NROWS; r0 += rc) {
        size_t rows = NROWS - r0;
        if (rows > rc) rows = rc;             // multiple of 128
        k_esplit<<<(unsigned)(rows * DIN / 1024), 256, 0, stream>>>(
            x + r0 * DIN, xcH, xcL, rows * DIN);
        // h1 = relu(x @ W1 + b1)
        k_gemm_split<0, 4><<<dim3(DH / 128, rows / 128), 256, 0, stream>>>(
            xcH, xcL, W1tH, W1tL, b1,
            h1H, h1L, nullptr, nullptr, nullptr, nullptr, (int)rows, DH, DIN);
        // h2 = h1 @ W2 + b2
        k_gemm_split<1, 4><<<dim3(DH / 128, rows / 128), 256, 0, stream>>>(
            h1H, h1L, W2tH, W2tL, b2,
            h2H, h2L, nullptr, nullptr, nullptr, nullptr, (int)rows, DH, DH);
        // z = h2 @ W3 + b3, with fused z2 row-norm accumulation (BM=64)
        k_gemm_split<2, 2><<<dim3(DZ / 128, rows / 64), 256, 0, stream>>>(
            h2H, h2L, W3tH, W3tL, b3,
            zH + r0 * DZ, zL + r0 * DZ, z2 + r0,
            nullptr, nullptr, nullptr, (int)rows, DZ, DH);
    }

    // ---- codebook norms + distance/argmin + outputs ----
    k_row_sq_norms<<<KCB / 4, 256, 0, stream>>>(cb, c2, DZ, KCB);

    k_gemm_split<3, 4><<<dim3(KCB / 128, NROWS / 128), 256, 0, stream>>>(
        zH, zL, cbH, cbL, nullptr,
        nullptr, nullptr, nullptr, z2, c2, best, NROWS, KCB, DZ);

    k_loss<<<1, 256, 0, stream>>>(best, out);
    k_output<<<NROWS, 64, 0, stream>>>(cb, best, out);
}